// Round 1
// 1209.983 us; speedup vs baseline: 1.1303x; 1.1303x over previous
//
#include <hip/hip_runtime.h>
#include <cstdint>

#define HW 25600
#define WIDTH 160
#define NB 8
#define DIM 192
#define CH2 384
#define PCH 288
#define HID 96
#define PROW 176
#define PPS 29216          // 166*176 padded plane (shorts)
#define OUTN 39321600      // 8*192*25600

typedef short bf16x8 __attribute__((ext_vector_type(8)));
typedef float f32x4 __attribute__((ext_vector_type(4)));

__device__ __forceinline__ unsigned short f2bf(float f) {
  union { float f; unsigned int u; } v; v.f = f;
  unsigned int u = v.u;
  u += 0x7FFFu + ((u >> 16) & 1u);
  return (unsigned short)(u >> 16);
}
__device__ __forceinline__ float bf2f(unsigned int bits16) {
  union { unsigned int u; float f; } v; v.u = bits16 << 16;
  return v.f;
}

// ---------------- K_prep: one-time bf16 convert of w_in (288x384 row-major) ----------------
__global__ void k_prep(const float* __restrict__ w, unsigned short* __restrict__ wa) {
  int i = blockIdx.x * 256 + threadIdx.x;          // 27648 threads x 4 elems = 110592
  float4 v = *(const float4*)(w + (size_t)i * 4);
  unsigned int lo = (unsigned int)f2bf(v.x) | ((unsigned int)f2bf(v.y) << 16);
  unsigned int hi = (unsigned int)f2bf(v.z) | ((unsigned int)f2bf(v.w) << 16);
  *(uint2*)(wa + (size_t)i * 4) = make_uint2(lo, hi);
}

// ---------------- K2: zero only the pad cells of the p buffer ----------------
__global__ void k_padzero(unsigned short* __restrict__ p) {
  unsigned short* base = p + (size_t)blockIdx.x * PPS;
  for (int i = threadIdx.x; i < 3616; i += 256) {
    int row, col;
    if (i < 1056) {               // 6 full pad rows (0,1,2,163,164,165)
      int r = i / PROW; col = i - r * PROW;
      row = (r < 3) ? r : 160 + r;
    } else {                      // 16 pad cols for the 160 interior rows
      int j = i - 1056;
      int r = j >> 4, cc = j & 15;
      row = 3 + r;
      col = (cc < 8) ? cc : 160 + cc;
    }
    base[row * PROW + col] = 0;
  }
}

// ---------------- K3a: h1 = relu(W1 @ y + b1) ----------------
__global__ void k_mlp1(const float* __restrict__ redsum, const float* __restrict__ redmax,
                       const float* __restrict__ w1, const float* __restrict__ b1,
                       float* __restrict__ h1) {
  int b = blockIdx.y;
  __shared__ float ybuf[768];
  int tid = threadIdx.x;
  for (int i = tid; i < 768; i += 256)
    ybuf[i] = (i < CH2) ? redsum[b * CH2 + i] * (1.0f / 25600.0f)
                        : redmax[b * CH2 + i - CH2];
  __syncthreads();
  int lane = tid & 63, wid = tid >> 6;
  int o0 = blockIdx.x * 256 + wid * 64;
  for (int oi = 0; oi < 64; ++oi) {
    int o = o0 + oi;
    const float* wr = w1 + (size_t)o * 768 + lane;
    float a = 0.f;
    #pragma unroll
    for (int j = 0; j < 12; ++j) a += wr[j * 64] * ybuf[lane + j * 64];
    #pragma unroll
    for (int k = 32; k >= 1; k >>= 1) a += __shfl_xor(a, k, 64);
    if (lane == 0) h1[b * 768 + o] = fmaxf(a + b1[o], 0.f);
  }
}

// ---------------- K3b: cw = sigmoid(W2 @ h1 + b2) ----------------
__global__ void k_mlp2(const float* __restrict__ h1, const float* __restrict__ w2,
                       const float* __restrict__ b2, float* __restrict__ cw) {
  int b = blockIdx.y;
  __shared__ float hbuf[768];
  int tid = threadIdx.x;
  for (int i = tid; i < 768; i += 256) hbuf[i] = h1[b * 768 + i];
  __syncthreads();
  int lane = tid & 63, wid = tid >> 6;
  int o0 = blockIdx.x * 256 + wid * 64;
  for (int oi = 0; oi < 64; ++oi) {
    int o = o0 + oi;
    if (o >= CH2) break;
    const float* wr = w2 + (size_t)o * 768 + lane;
    float a = 0.f;
    #pragma unroll
    for (int j = 0; j < 12; ++j) a += wr[j * 64] * hbuf[lane + j * 64];
    #pragma unroll
    for (int k = 32; k >= 1; k >>= 1) a += __shfl_xor(a, k, 64);
    if (lane == 0) cw[b * CH2 + o] = 1.f / (1.f + expf(-(a + b2[o])));
  }
}

// ---------------- K4: GEMM1 (atomic-free, A-from-L2, B double-buffered) ----------------
// Block: M-half (144 rows, mz in {0,1}) x 128 spatial. Single barrier per K-step.
#define G1_ST 72
__global__ __launch_bounds__(256, 2)
void k_gemm1(const float* __restrict__ x1, const float* __restrict__ x2,
             const unsigned short* __restrict__ wa, unsigned short* __restrict__ p,
             float* __restrict__ partial) {
  __shared__ short Blds[2][128 * G1_ST];   // double-buffered 128(s) x 64(k) bf16, stride 72
  __shared__ float psum[CH2];              // per-block channel partial sums (no atomics)
  __shared__ float pmax[CH2];              // per-block channel partial maxes
  int tid = threadIdx.x;
  int bx = blockIdx.x, mz = blockIdx.y, b = blockIdx.z;
  int ns = bx * 128;
  int lane = tid & 63, wid = tid >> 6;
  int quad = lane >> 4, l15 = lane & 15;
  int wn = wid;                 // 4 waves, 32 spatial cols each
  int sg = tid & 31, cg0 = tid >> 5;
  int s4 = sg << 2;

  f32x4 acc[9][2];
  #pragma unroll
  for (int i = 0; i < 9; ++i) {
    acc[i][0] = (f32x4){0.f, 0.f, 0.f, 0.f};
    acc[i][1] = (f32x4){0.f, 0.f, 0.f, 0.f};
  }

  float4 R[8];   // in-flight B tile (2 its x 4 channel-rows)

#define ISSUE_B(KK) do { \
    int kc_ = (KK) * 64; \
    const float* xb_ = (kc_ < DIM) ? (x1 + ((size_t)b * DIM + kc_) * HW) \
                                   : (x2 + ((size_t)b * DIM + (kc_ - DIM)) * HW); \
    _Pragma("unroll") \
    for (int it = 0; it < 2; ++it) { \
      const float* src_ = xb_ + (size_t)((cg0 + it * 8) << 2) * HW + ns + s4; \
      R[it * 4 + 0] = *(const float4*)(src_); \
      R[it * 4 + 1] = *(const float4*)(src_ + HW); \
      R[it * 4 + 2] = *(const float4*)(src_ + 2 * HW); \
      R[it * 4 + 3] = *(const float4*)(src_ + 3 * HW); \
    } \
  } while (0)

#define CONVERT_B(KK, BI) do { \
    int kc_ = (KK) * 64; \
    _Pragma("unroll") \
    for (int it = 0; it < 2; ++it) { \
      int c4_ = (cg0 + it * 8) << 2; \
      float4 r0 = R[it * 4 + 0], r1 = R[it * 4 + 1], r2 = R[it * 4 + 2], r3 = R[it * 4 + 3]; \
      unsigned short t0[4] = {f2bf(r0.x), f2bf(r0.y), f2bf(r0.z), f2bf(r0.w)}; \
      unsigned short t1[4] = {f2bf(r1.x), f2bf(r1.y), f2bf(r1.z), f2bf(r1.w)}; \
      unsigned short t2[4] = {f2bf(r2.x), f2bf(r2.y), f2bf(r2.z), f2bf(r2.w)}; \
      unsigned short t3[4] = {f2bf(r3.x), f2bf(r3.y), f2bf(r3.z), f2bf(r3.w)}; \
      _Pragma("unroll") \
      for (int j = 0; j < 4; ++j) { \
        unsigned int lo = (unsigned int)t0[j] | ((unsigned int)t1[j] << 16); \
        unsigned int hi = (unsigned int)t2[j] | ((unsigned int)t3[j] << 16); \
        *(uint2*)&Blds[BI][(s4 + j) * G1_ST + c4_] = make_uint2(lo, hi); \
      } \
      if (mz == 0) { \
        float s0 = r0.x + r0.y + r0.z + r0.w; \
        float s1 = r1.x + r1.y + r1.z + r1.w; \
        float s2 = r2.x + r2.y + r2.z + r2.w; \
        float s3 = r3.x + r3.y + r3.z + r3.w; \
        float m0 = fmaxf(fmaxf(r0.x, r0.y), fmaxf(r0.z, r0.w)); \
        float m1 = fmaxf(fmaxf(r1.x, r1.y), fmaxf(r1.z, r1.w)); \
        float m2 = fmaxf(fmaxf(r2.x, r2.y), fmaxf(r2.z, r2.w)); \
        float m3 = fmaxf(fmaxf(r3.x, r3.y), fmaxf(r3.z, r3.w)); \
        _Pragma("unroll") \
        for (int msk = 16; msk >= 1; msk >>= 1) { \
          s0 += __shfl_xor(s0, msk, 64); \
          s1 += __shfl_xor(s1, msk, 64); \
          s2 += __shfl_xor(s2, msk, 64); \
          s3 += __shfl_xor(s3, msk, 64); \
          m0 = fmaxf(m0, __shfl_xor(m0, msk, 64)); \
          m1 = fmaxf(m1, __shfl_xor(m1, msk, 64)); \
          m2 = fmaxf(m2, __shfl_xor(m2, msk, 64)); \
          m3 = fmaxf(m3, __shfl_xor(m3, msk, 64)); \
        } \
        if ((tid & 31) == 0) { \
          int ch_ = kc_ + c4_; \
          psum[ch_ + 0] = s0; psum[ch_ + 1] = s1; psum[ch_ + 2] = s2; psum[ch_ + 3] = s3; \
          pmax[ch_ + 0] = m0; pmax[ch_ + 1] = m1; pmax[ch_ + 2] = m2; pmax[ch_ + 3] = m3; \
        } \
      } \
    } \
  } while (0)

#define DO_MFMA(KK, BI) do { \
    const unsigned short* wab_ = wa + (size_t)(mz * 144 + l15) * CH2 + (KK) * 64 + quad * 8; \
    _Pragma("unroll") \
    for (int ks = 0; ks < 2; ++ks) { \
      int kof_ = ks * 32 + quad * 8; \
      bf16x8 b0_ = *(const bf16x8*)&Blds[BI][(wn * 32 + l15) * G1_ST + kof_]; \
      bf16x8 b1_ = *(const bf16x8*)&Blds[BI][(wn * 32 + 16 + l15) * G1_ST + kof_]; \
      _Pragma("unroll") \
      for (int mt = 0; mt < 9; ++mt) { \
        bf16x8 af_ = *(const bf16x8*)(wab_ + (size_t)mt * (16 * CH2) + ks * 32); \
        acc[mt][0] = __builtin_amdgcn_mfma_f32_16x16x32_bf16(af_, b0_, acc[mt][0], 0, 0, 0); \
        acc[mt][1] = __builtin_amdgcn_mfma_f32_16x16x32_bf16(af_, b1_, acc[mt][1], 0, 0, 0); \
      } \
    } \
  } while (0)

  // software pipeline: one barrier per K-step, B(kk+1) loads in flight over MFMA(kk)
  ISSUE_B(0);
  CONVERT_B(0, 0);
  ISSUE_B(1);
  __syncthreads();
  #pragma unroll
  for (int kk = 0; kk < 6; ++kk) {
    DO_MFMA(kk, kk & 1);
    if (kk < 5) {
      CONVERT_B(kk + 1, (kk + 1) & 1);
      if (kk < 4) ISSUE_B(kk + 2);
      __syncthreads();
    }
  }

#undef ISSUE_B
#undef CONVERT_B
#undef DO_MFMA

  // epilogue: bf16 store into padded p
  unsigned short* pb = p + (size_t)b * PCH * PPS;
  #pragma unroll
  for (int mt = 0; mt < 9; ++mt) {
    int obase = mz * 144 + mt * 16 + quad * 4;
    #pragma unroll
    for (int nt = 0; nt < 2; ++nt) {
      int s = ns + wn * 32 + nt * 16 + l15;
      int yy = s / WIDTH;
      int xx = s - yy * WIDTH;
      #pragma unroll
      for (int r = 0; r < 4; ++r) {
        int o = obase + r;
        pb[(size_t)o * PPS + (size_t)(yy + 3) * PROW + xx + 8] = f2bf(acc[mt][nt][r]);
      }
    }
  }

  // per-block reduction partials -> global (only the mz==0 copy of each x-tile)
  if (mz == 0) {
    float* pp = partial + ((size_t)bx * 8 + b) * 768;
    for (int i = tid; i < 384; i += 256) {
      pp[i] = psum[i];
      pp[384 + i] = pmax[i];
    }
  }
}

// ---------------- K4b: fold 200 per-block partials -> redsum/redmax ----------------
__global__ void k_reduce(const float* __restrict__ partial, float* __restrict__ redsum,
                         float* __restrict__ redmax) {
  int col = blockIdx.x * 256 + threadIdx.x;     // 0..6143
  int b = col / 768, j = col - b * 768;
  const float* src = partial + col;
  bool isSum = (j < 384);                        // wave-uniform (384 % 64 == 0)
  float a0, a1, a2, a3;
  if (isSum) { a0 = a1 = a2 = a3 = 0.f; }
  else       { a0 = a1 = a2 = a3 = -3.402823466e38f; }
  #pragma unroll 2
  for (int i = 0; i < 200; i += 4) {
    float v0 = src[(size_t)(i + 0) * 6144];
    float v1 = src[(size_t)(i + 1) * 6144];
    float v2 = src[(size_t)(i + 2) * 6144];
    float v3 = src[(size_t)(i + 3) * 6144];
    if (isSum) { a0 += v0; a1 += v1; a2 += v2; a3 += v3; }
    else { a0 = fmaxf(a0, v0); a1 = fmaxf(a1, v1); a2 = fmaxf(a2, v2); a3 = fmaxf(a3, v3); }
  }
  if (isSum) redsum[b * CH2 + j] = (a0 + a1) + (a2 + a3);
  else       redmax[b * CH2 + (j - 384)] = fmaxf(fmaxf(a0, a1), fmaxf(a2, a3));
}

// ---------------- K5: depthwise convs (dil 1/2/3) + GELU gate, LDS-tiled ----------------
#define TH 16
__global__ __launch_bounds__(256)
void k_dwgelu(const unsigned short* __restrict__ p,
              const float* __restrict__ wd1, const float* __restrict__ wd2,
              const float* __restrict__ wd3, unsigned short* __restrict__ g) {
  __shared__ unsigned lds[(18 + 20 + 22) * 88];   // 21120 B
  unsigned* la = lds;                // 18 rows (global y0-1 .. y0+16)
  unsigned* l2 = lds + 18 * 88;      // 20 rows (y0-2 .. y0+17)
  unsigned* l3 = lds + 38 * 88;      // 22 rows (y0-3 .. y0+18)

  int rg = blockIdx.x, c = blockIdx.y, b = blockIdx.z;
  int y0 = rg * TH;
  int tid = threadIdx.x;

  const unsigned short* pa = p + ((size_t)(b * PCH) + c) * PPS;
  const unsigned* srcA = (const unsigned*)(pa + (size_t)(y0 + 2) * PROW);
  const unsigned* src2 = (const unsigned*)(pa + (size_t)96 * PPS + (size_t)(y0 + 1) * PROW);
  const unsigned* src3 = (const unsigned*)(pa + (size_t)192 * PPS + (size_t)y0 * PROW);
  for (int i = tid; i < 18 * 88; i += 256) la[i] = srcA[i];
  for (int i = tid; i < 20 * 88; i += 256) l2[i] = src2[i];
  for (int i = tid; i < 22 * 88; i += 256) l3[i] = src3[i];

  float w1r[9], w2r[9], w3r[9];
  #pragma unroll
  for (int i = 0; i < 9; ++i) { w1r[i] = wd1[c * 9 + i]; w2r[i] = wd2[c * 9 + i]; w3r[i] = wd3[c * 9 + i]; }
  __syncthreads();

  int oy = tid >> 4;            // 0..15
  int cg = tid & 15;
  int ox0 = cg * 10;            // 0..150
  int ub = 3 + (ox0 >> 1);      // uint col base for a/g2 (px col 6+ox0)
  int ub3 = 2 + (ox0 >> 1);     // uint col base for g3  (px col 4+ox0)

  float acc_a[10], acc_g[10];
  #pragma unroll
  for (int i = 0; i < 10; ++i) { acc_a[i] = 0.f; acc_g[i] = 0.f; }

  // plane a (dil 1)
  #pragma unroll
  for (int ky = 0; ky < 3; ++ky) {
    const unsigned* rp = la + (oy + ky) * 88 + ub;
    float v[14];
    #pragma unroll
    for (int u = 0; u < 7; ++u) { unsigned d = rp[u]; v[2 * u] = bf2f(d & 0xFFFFu); v[2 * u + 1] = bf2f(d >> 16); }
    #pragma unroll
    for (int kx = 0; kx < 3; ++kx) {
      float wv = w1r[ky * 3 + kx];
      #pragma unroll
      for (int i = 0; i < 10; ++i) acc_a[i] += wv * v[i + kx + 1];
    }
  }
  // plane g2 (dil 2)
  #pragma unroll
  for (int ky = 0; ky < 3; ++ky) {
    const unsigned* rp = l2 + (oy + 2 * ky) * 88 + ub;
    float v[14];
    #pragma unroll
    for (int u = 0; u < 7; ++u) { unsigned d = rp[u]; v[2 * u] = bf2f(d & 0xFFFFu); v[2 * u + 1] = bf2f(d >> 16); }
    #pragma unroll
    for (int kx = 0; kx < 3; ++kx) {
      float wv = w2r[ky * 3 + kx];
      #pragma unroll
      for (int i = 0; i < 10; ++i) acc_g[i] += wv * v[i + 2 * kx];
    }
  }
  // plane g3 (dil 3)
  #pragma unroll
  for (int ky = 0; ky < 3; ++ky) {
    const unsigned* rp = l3 + (oy + 3 * ky) * 88 + ub3;
    float v[18];
    #pragma unroll
    for (int u = 0; u < 9; ++u) { unsigned d = rp[u]; v[2 * u] = bf2f(d & 0xFFFFu); v[2 * u + 1] = bf2f(d >> 16); }
    #pragma unroll
    for (int kx = 0; kx < 3; ++kx) {
      float wv = w3r[ky * 3 + kx];
      #pragma unroll
      for (int i = 0; i < 10; ++i) acc_g[i] += wv * v[i + 3 * kx + 1];
    }
  }

  unsigned short* gp = g + ((size_t)(b * HID) + c) * HW + (size_t)(y0 + oy) * WIDTH + ox0;
  #pragma unroll
  for (int j = 0; j < 5; ++j) {
    float a0 = acc_a[2 * j], a1 = acc_a[2 * j + 1];
    float g0 = 0.5f * a0 * (1.f + erff(a0 * 0.70710678118f)) * acc_g[2 * j];
    float g1 = 0.5f * a1 * (1.f + erff(a1 * 0.70710678118f)) * acc_g[2 * j + 1];
    ((unsigned*)gp)[j] = (unsigned)f2bf(g0) | ((unsigned)f2bf(g1) << 16);
  }
}

// ---------------- K6: GEMM2 (96->384) + residual/channel-weight fuse ----------------
#define G2_ST 104
__global__ __launch_bounds__(256, 2)
void k_gemm2(const unsigned short* __restrict__ g, const float* __restrict__ w_out,
             const float* __restrict__ x1, const float* __restrict__ x2,
             const float* __restrict__ cw, float* __restrict__ out) {
  __shared__ short Alds[128 * G2_ST];
  __shared__ short Blds[128 * G2_ST];
  int tid = threadIdx.x;
  int ns = blockIdx.x * 128;
  int mo = blockIdx.y * 128;
  int b = blockIdx.z;
  int lane = tid & 63, wid = tid >> 6;
  int quad = lane >> 4, l15 = lane & 15;
  int wm = wid >> 1, wn = wid & 1;

  // stage A: w_out[mo..mo+127][0..95]
  #pragma unroll
  for (int i = 0; i < 12; ++i) {
    int idx = i * 256 + tid;
    int row = idx / 24, c4 = (idx % 24) * 4;
    float4 w4 = *(const float4*)(w_out + (size_t)(mo + row) * HID + c4);
    unsigned int lo = (unsigned int)f2bf(w4.x) | ((unsigned int)f2bf(w4.y) << 16);
    unsigned int hi = (unsigned int)f2bf(w4.z) | ((unsigned int)f2bf(w4.w) << 16);
    *(uint2*)&Alds[row * G2_ST + c4] = make_uint2(lo, hi);
  }
  // stage B: g[0..95][ns..ns+127] transposed into Blds[s][c]
  const unsigned short* gb = g + (size_t)b * HID * HW;
  #pragma unroll
  for (int it = 0; it < 3; ++it) {
    int idx = it * 256 + tid;
    int sg = idx & 31, cg = idx >> 5;
    int c4 = cg * 4, s4 = sg * 4;
    const unsigned short* src = gb + (size_t)c4 * HW + ns + s4;
    uint2 r0 = *(const uint2*)(src);
    uint2 r1 = *(const uint2*)(src + HW);
    uint2 r2 = *(const uint2*)(src + 2 * HW);
    uint2 r3 = *(const uint2*)(src + 3 * HW);
    unsigned short e0[4] = {(unsigned short)r0.x, (unsigned short)(r0.x >> 16), (unsigned short)r0.y, (unsigned short)(r0.y >> 16)};
    unsigned short e1[4] = {(unsigned short)r1.x, (unsigned short)(r1.x >> 16), (unsigned short)r1.y, (unsigned short)(r1.y >> 16)};
    unsigned short e2[4] = {(unsigned short)r2.x, (unsigned short)(r2.x >> 16), (unsigned short)r2.y, (unsigned short)(r2.y >> 16)};
    unsigned short e3[4] = {(unsigned short)r3.x, (unsigned short)(r3.x >> 16), (unsigned short)r3.y, (unsigned short)(r3.y >> 16)};
    #pragma unroll
    for (int j = 0; j < 4; ++j) {
      unsigned int lo = (unsigned int)e0[j] | ((unsigned int)e1[j] << 16);
      unsigned int hi = (unsigned int)e2[j] | ((unsigned int)e3[j] << 16);
      *(uint2*)&Blds[(s4 + j) * G2_ST + c4] = make_uint2(lo, hi);
    }
  }
  __syncthreads();

  f32x4 acc[4][4];
  #pragma unroll
  for (int i = 0; i < 4; ++i) {
    #pragma unroll
    for (int j = 0; j < 4; ++j) acc[i][j] = (f32x4){0.f, 0.f, 0.f, 0.f};
  }
  #pragma unroll
  for (int ks = 0; ks < 3; ++ks) {
    int kof = ks * 32 + quad * 8;
    bf16x8 bfr[4];
    #pragma unroll
    for (int nt = 0; nt < 4; ++nt)
      bfr[nt] = *(const bf16x8*)&Blds[(wn * 64 + nt * 16 + l15) * G2_ST + kof];
    #pragma unroll
    for (int mt = 0; mt < 4; ++mt) {
      bf16x8 af = *(const bf16x8*)&Alds[(wm * 64 + mt * 16 + l15) * G2_ST + kof];
      #pragma unroll
      for (int nt = 0; nt < 4; ++nt)
        acc[mt][nt] = __builtin_amdgcn_mfma_f32_16x16x32_bf16(af, bfr[nt], acc[mt][nt], 0, 0, 0);
    }
  }

  const float* cwb = cw + b * CH2;
  #pragma unroll
  for (int mt = 0; mt < 4; ++mt) {
    int o2b = mo + wm * 64 + mt * 16 + quad * 4;
    #pragma unroll
    for (int nt = 0; nt < 4; ++nt) {
      int s = ns + wn * 64 + nt * 16 + l15;
      #pragma unroll
      for (int r = 0; r < 4; ++r) {
        int o2 = o2b + r;
        int cch = (o2 < DIM) ? o2 : (o2 - DIM);
        size_t coff = ((size_t)b * DIM + cch) * HW + s;
        float v1 = x1[coff], v2 = x2[coff];
        float cwv = cwb[o2];
        float swv = acc[mt][nt][r];
        if (o2 < DIM) {
          out[OUTN + coff] = v2 + 0.5f * cwv * v1 + 0.5f * swv;   // out_x2
        } else {
          out[coff] = v1 + 0.5f * cwv * v2 + 0.5f * swv;          // out_x1
        }
      }
    }
  }
}

extern "C" void kernel_launch(void* const* d_in, const int* in_sizes, int n_in,
                              void* d_out, int out_size, void* d_ws, size_t ws_size,
                              hipStream_t stream) {
  const float* x1 = (const float*)d_in[0];
  const float* x2 = (const float*)d_in[1];
  const float* mlp_w1 = (const float*)d_in[2];
  const float* mlp_b1 = (const float*)d_in[3];
  const float* mlp_w2 = (const float*)d_in[4];
  const float* mlp_b2 = (const float*)d_in[5];
  const float* w_in = (const float*)d_in[6];
  const float* w_dw1 = (const float*)d_in[7];
  const float* w_dw2 = (const float*)d_in[8];
  const float* w_dw3 = (const float*)d_in[9];
  const float* w_out = (const float*)d_in[10];
  float* out = (float*)d_out;

  char* ws = (char*)d_ws;
  float* redsum       = (float*)(ws + 0);           // 3072 f
  float* redmax       = (float*)(ws + 12288);       // 3072 f
  float* h1           = (float*)(ws + 24576);       // 6144 f
  float* cw           = (float*)(ws + 49152);       // 3072 f
  unsigned short* p = (unsigned short*)(ws + 65536);             // 8*288*29216 bf16
  char* gbase = ws + 65536 + 134627328;
  unsigned short* g = (unsigned short*)gbase;                    // 8*96*25600 bf16
  // partial (4.92 MB) and wA (221 KB) overlap g's region: both are dead before
  // k_dwgelu writes g (stream-ordered), so no extra workspace is needed.
  float* partial      = (float*)gbase;                           // 200*8*768 f
  unsigned short* wA  = (unsigned short*)(gbase + 8388608);      // 288*384 bf16

  k_prep   <<<dim3(108),         dim3(256), 0, stream>>>(w_in, wA);
  k_padzero<<<dim3(2304),        dim3(256), 0, stream>>>(p);
  k_gemm1  <<<dim3(200, 2, 8),   dim3(256), 0, stream>>>(x1, x2, wA, p, partial);
  k_reduce <<<dim3(24),          dim3(256), 0, stream>>>(partial, redsum, redmax);
  k_mlp1   <<<dim3(3, 8),        dim3(256), 0, stream>>>(redsum, redmax, mlp_w1, mlp_b1, h1);
  k_mlp2   <<<dim3(2, 8),        dim3(256), 0, stream>>>(h1, mlp_w2, mlp_b2, cw);
  k_dwgelu <<<dim3(10, 96, 8),   dim3(256), 0, stream>>>(p, w_dw1, w_dw2, w_dw3, g);
  k_gemm2  <<<dim3(200, 3, 8),   dim3(256), 0, stream>>>(g, w_out, x1, x2, cw, out);
}

// Round 2
// 1089.424 us; speedup vs baseline: 1.2553x; 1.1107x over previous
//
#include <hip/hip_runtime.h>
#include <cstdint>

#define HW 25600
#define WIDTH 160
#define NB 8
#define DIM 192
#define CH2 384
#define PCH 288
#define HID 96
#define PROW 176
#define PPS 29216          // 166*176 padded plane (shorts)
#define OUTN 39321600      // 8*192*25600

typedef short bf16x8 __attribute__((ext_vector_type(8)));
typedef float f32x4 __attribute__((ext_vector_type(4)));

__device__ __forceinline__ unsigned short f2bf(float f) {
  union { float f; unsigned int u; } v; v.f = f;
  unsigned int u = v.u;
  u += 0x7FFFu + ((u >> 16) & 1u);
  return (unsigned short)(u >> 16);
}
__device__ __forceinline__ float bf2f(unsigned int bits16) {
  union { unsigned int u; float f; } v; v.u = bits16 << 16;
  return v.f;
}

// ---------------- K_prep: one-time bf16 convert of w_in (288x384 row-major) ----------------
__global__ void k_prep(const float* __restrict__ w, unsigned short* __restrict__ wa) {
  int i = blockIdx.x * 256 + threadIdx.x;          // 27648 threads x 4 elems = 110592
  float4 v = *(const float4*)(w + (size_t)i * 4);
  unsigned int lo = (unsigned int)f2bf(v.x) | ((unsigned int)f2bf(v.y) << 16);
  unsigned int hi = (unsigned int)f2bf(v.z) | ((unsigned int)f2bf(v.w) << 16);
  *(uint2*)(wa + (size_t)i * 4) = make_uint2(lo, hi);
}

// ---------------- K_prep2: bf16 convert of w_out (384x96 row-major), into dead p region ----
__global__ void k_prep2(const float* __restrict__ w, unsigned short* __restrict__ wo) {
  int i = blockIdx.x * 256 + threadIdx.x;          // 9216 threads x 4 elems = 36864
  float4 v = *(const float4*)(w + (size_t)i * 4);
  unsigned int lo = (unsigned int)f2bf(v.x) | ((unsigned int)f2bf(v.y) << 16);
  unsigned int hi = (unsigned int)f2bf(v.z) | ((unsigned int)f2bf(v.w) << 16);
  *(uint2*)(wo + (size_t)i * 4) = make_uint2(lo, hi);
}

// ---------------- K2: zero only the pad cells of the p buffer ----------------
__global__ void k_padzero(unsigned short* __restrict__ p) {
  unsigned short* base = p + (size_t)blockIdx.x * PPS;
  for (int i = threadIdx.x; i < 3616; i += 256) {
    int row, col;
    if (i < 1056) {               // 6 full pad rows (0,1,2,163,164,165)
      int r = i / PROW; col = i - r * PROW;
      row = (r < 3) ? r : 160 + r;
    } else {                      // 16 pad cols for the 160 interior rows
      int j = i - 1056;
      int r = j >> 4, cc = j & 15;
      row = 3 + r;
      col = (cc < 8) ? cc : 160 + cc;
    }
    base[row * PROW + col] = 0;
  }
}

// ---------------- K3a: h1 = relu(W1 @ y + b1) ----------------
__global__ void k_mlp1(const float* __restrict__ redsum, const float* __restrict__ redmax,
                       const float* __restrict__ w1, const float* __restrict__ b1,
                       float* __restrict__ h1) {
  int b = blockIdx.y;
  __shared__ float ybuf[768];
  int tid = threadIdx.x;
  for (int i = tid; i < 768; i += 256)
    ybuf[i] = (i < CH2) ? redsum[b * CH2 + i] * (1.0f / 25600.0f)
                        : redmax[b * CH2 + i - CH2];
  __syncthreads();
  int lane = tid & 63, wid = tid >> 6;
  int o0 = blockIdx.x * 256 + wid * 64;
  for (int oi = 0; oi < 64; ++oi) {
    int o = o0 + oi;
    const float* wr = w1 + (size_t)o * 768 + lane;
    float a = 0.f;
    #pragma unroll
    for (int j = 0; j < 12; ++j) a += wr[j * 64] * ybuf[lane + j * 64];
    #pragma unroll
    for (int k = 32; k >= 1; k >>= 1) a += __shfl_xor(a, k, 64);
    if (lane == 0) h1[b * 768 + o] = fmaxf(a + b1[o], 0.f);
  }
}

// ---------------- K3b: cw = sigmoid(W2 @ h1 + b2) ----------------
__global__ void k_mlp2(const float* __restrict__ h1, const float* __restrict__ w2,
                       const float* __restrict__ b2, float* __restrict__ cw) {
  int b = blockIdx.y;
  __shared__ float hbuf[768];
  int tid = threadIdx.x;
  for (int i = tid; i < 768; i += 256) hbuf[i] = h1[b * 768 + i];
  __syncthreads();
  int lane = tid & 63, wid = tid >> 6;
  int o0 = blockIdx.x * 256 + wid * 64;
  for (int oi = 0; oi < 64; ++oi) {
    int o = o0 + oi;
    if (o >= CH2) break;
    const float* wr = w2 + (size_t)o * 768 + lane;
    float a = 0.f;
    #pragma unroll
    for (int j = 0; j < 12; ++j) a += wr[j * 64] * hbuf[lane + j * 64];
    #pragma unroll
    for (int k = 32; k >= 1; k >>= 1) a += __shfl_xor(a, k, 64);
    if (lane == 0) cw[b * CH2 + o] = 1.f / (1.f + expf(-(a + b2[o])));
  }
}

// ---------------- K4: GEMM1 (atomic-free, A-from-L2, B double-buffered) ----------------
// Block: M-half (144 rows, mz in {0,1}) x 128 spatial. Single barrier per K-step.
#define G1_ST 72
__global__ __launch_bounds__(256, 2)
void k_gemm1(const float* __restrict__ x1, const float* __restrict__ x2,
             const unsigned short* __restrict__ wa, unsigned short* __restrict__ p,
             float* __restrict__ partial) {
  __shared__ short Blds[2][128 * G1_ST];   // double-buffered 128(s) x 64(k) bf16, stride 72
  __shared__ float psum[CH2];              // per-block channel partial sums (no atomics)
  __shared__ float pmax[CH2];              // per-block channel partial maxes
  int tid = threadIdx.x;
  int bx = blockIdx.x, mz = blockIdx.y, b = blockIdx.z;
  int ns = bx * 128;
  int lane = tid & 63, wid = tid >> 6;
  int quad = lane >> 4, l15 = lane & 15;
  int wn = wid;                 // 4 waves, 32 spatial cols each
  int sg = tid & 31, cg0 = tid >> 5;
  int s4 = sg << 2;

  f32x4 acc[9][2];
  #pragma unroll
  for (int i = 0; i < 9; ++i) {
    acc[i][0] = (f32x4){0.f, 0.f, 0.f, 0.f};
    acc[i][1] = (f32x4){0.f, 0.f, 0.f, 0.f};
  }

  float4 R[8];   // in-flight B tile (2 its x 4 channel-rows)

#define ISSUE_B(KK) do { \
    int kc_ = (KK) * 64; \
    const float* xb_ = (kc_ < DIM) ? (x1 + ((size_t)b * DIM + kc_) * HW) \
                                   : (x2 + ((size_t)b * DIM + (kc_ - DIM)) * HW); \
    _Pragma("unroll") \
    for (int it = 0; it < 2; ++it) { \
      const float* src_ = xb_ + (size_t)((cg0 + it * 8) << 2) * HW + ns + s4; \
      R[it * 4 + 0] = *(const float4*)(src_); \
      R[it * 4 + 1] = *(const float4*)(src_ + HW); \
      R[it * 4 + 2] = *(const float4*)(src_ + 2 * HW); \
      R[it * 4 + 3] = *(const float4*)(src_ + 3 * HW); \
    } \
  } while (0)

#define CONVERT_B(KK, BI) do { \
    int kc_ = (KK) * 64; \
    _Pragma("unroll") \
    for (int it = 0; it < 2; ++it) { \
      int c4_ = (cg0 + it * 8) << 2; \
      float4 r0 = R[it * 4 + 0], r1 = R[it * 4 + 1], r2 = R[it * 4 + 2], r3 = R[it * 4 + 3]; \
      unsigned short t0[4] = {f2bf(r0.x), f2bf(r0.y), f2bf(r0.z), f2bf(r0.w)}; \
      unsigned short t1[4] = {f2bf(r1.x), f2bf(r1.y), f2bf(r1.z), f2bf(r1.w)}; \
      unsigned short t2[4] = {f2bf(r2.x), f2bf(r2.y), f2bf(r2.z), f2bf(r2.w)}; \
      unsigned short t3[4] = {f2bf(r3.x), f2bf(r3.y), f2bf(r3.z), f2bf(r3.w)}; \
      _Pragma("unroll") \
      for (int j = 0; j < 4; ++j) { \
        unsigned int lo = (unsigned int)t0[j] | ((unsigned int)t1[j] << 16); \
        unsigned int hi = (unsigned int)t2[j] | ((unsigned int)t3[j] << 16); \
        *(uint2*)&Blds[BI][(s4 + j) * G1_ST + c4_] = make_uint2(lo, hi); \
      } \
      if (mz == 0) { \
        float s0 = r0.x + r0.y + r0.z + r0.w; \
        float s1 = r1.x + r1.y + r1.z + r1.w; \
        float s2 = r2.x + r2.y + r2.z + r2.w; \
        float s3 = r3.x + r3.y + r3.z + r3.w; \
        float m0 = fmaxf(fmaxf(r0.x, r0.y), fmaxf(r0.z, r0.w)); \
        float m1 = fmaxf(fmaxf(r1.x, r1.y), fmaxf(r1.z, r1.w)); \
        float m2 = fmaxf(fmaxf(r2.x, r2.y), fmaxf(r2.z, r2.w)); \
        float m3 = fmaxf(fmaxf(r3.x, r3.y), fmaxf(r3.z, r3.w)); \
        _Pragma("unroll") \
        for (int msk = 16; msk >= 1; msk >>= 1) { \
          s0 += __shfl_xor(s0, msk, 64); \
          s1 += __shfl_xor(s1, msk, 64); \
          s2 += __shfl_xor(s2, msk, 64); \
          s3 += __shfl_xor(s3, msk, 64); \
          m0 = fmaxf(m0, __shfl_xor(m0, msk, 64)); \
          m1 = fmaxf(m1, __shfl_xor(m1, msk, 64)); \
          m2 = fmaxf(m2, __shfl_xor(m2, msk, 64)); \
          m3 = fmaxf(m3, __shfl_xor(m3, msk, 64)); \
        } \
        if ((tid & 31) == 0) { \
          int ch_ = kc_ + c4_; \
          psum[ch_ + 0] = s0; psum[ch_ + 1] = s1; psum[ch_ + 2] = s2; psum[ch_ + 3] = s3; \
          pmax[ch_ + 0] = m0; pmax[ch_ + 1] = m1; pmax[ch_ + 2] = m2; pmax[ch_ + 3] = m3; \
        } \
      } \
    } \
  } while (0)

#define DO_MFMA(KK, BI) do { \
    const unsigned short* wab_ = wa + (size_t)(mz * 144 + l15) * CH2 + (KK) * 64 + quad * 8; \
    _Pragma("unroll") \
    for (int ks = 0; ks < 2; ++ks) { \
      int kof_ = ks * 32 + quad * 8; \
      bf16x8 b0_ = *(const bf16x8*)&Blds[BI][(wn * 32 + l15) * G1_ST + kof_]; \
      bf16x8 b1_ = *(const bf16x8*)&Blds[BI][(wn * 32 + 16 + l15) * G1_ST + kof_]; \
      _Pragma("unroll") \
      for (int mt = 0; mt < 9; ++mt) { \
        bf16x8 af_ = *(const bf16x8*)(wab_ + (size_t)mt * (16 * CH2) + ks * 32); \
        acc[mt][0] = __builtin_amdgcn_mfma_f32_16x16x32_bf16(af_, b0_, acc[mt][0], 0, 0, 0); \
        acc[mt][1] = __builtin_amdgcn_mfma_f32_16x16x32_bf16(af_, b1_, acc[mt][1], 0, 0, 0); \
      } \
    } \
  } while (0)

  // software pipeline: one barrier per K-step, B(kk+1) loads in flight over MFMA(kk)
  ISSUE_B(0);
  CONVERT_B(0, 0);
  ISSUE_B(1);
  __syncthreads();
  #pragma unroll
  for (int kk = 0; kk < 6; ++kk) {
    DO_MFMA(kk, kk & 1);
    if (kk < 5) {
      CONVERT_B(kk + 1, (kk + 1) & 1);
      if (kk < 4) ISSUE_B(kk + 2);
      __syncthreads();
    }
  }

#undef ISSUE_B
#undef CONVERT_B
#undef DO_MFMA

  // epilogue: bf16 store into padded p
  unsigned short* pb = p + (size_t)b * PCH * PPS;
  #pragma unroll
  for (int mt = 0; mt < 9; ++mt) {
    int obase = mz * 144 + mt * 16 + quad * 4;
    #pragma unroll
    for (int nt = 0; nt < 2; ++nt) {
      int s = ns + wn * 32 + nt * 16 + l15;
      int yy = s / WIDTH;
      int xx = s - yy * WIDTH;
      #pragma unroll
      for (int r = 0; r < 4; ++r) {
        int o = obase + r;
        pb[(size_t)o * PPS + (size_t)(yy + 3) * PROW + xx + 8] = f2bf(acc[mt][nt][r]);
      }
    }
  }

  // per-block reduction partials -> global (only the mz==0 copy of each x-tile)
  if (mz == 0) {
    float* pp = partial + ((size_t)bx * 8 + b) * 768;
    for (int i = tid; i < 384; i += 256) {
      pp[i] = psum[i];
      pp[384 + i] = pmax[i];
    }
  }
}

// ---------------- K4b: fold 200 per-block partials -> redsum/redmax ----------------
__global__ void k_reduce(const float* __restrict__ partial, float* __restrict__ redsum,
                         float* __restrict__ redmax) {
  int col = blockIdx.x * 256 + threadIdx.x;     // 0..6143
  int b = col / 768, j = col - b * 768;
  const float* src = partial + col;
  bool isSum = (j < 384);                        // wave-uniform (384 % 64 == 0)
  float a0, a1, a2, a3;
  if (isSum) { a0 = a1 = a2 = a3 = 0.f; }
  else       { a0 = a1 = a2 = a3 = -3.402823466e38f; }
  #pragma unroll 2
  for (int i = 0; i < 200; i += 4) {
    float v0 = src[(size_t)(i + 0) * 6144];
    float v1 = src[(size_t)(i + 1) * 6144];
    float v2 = src[(size_t)(i + 2) * 6144];
    float v3 = src[(size_t)(i + 3) * 6144];
    if (isSum) { a0 += v0; a1 += v1; a2 += v2; a3 += v3; }
    else { a0 = fmaxf(a0, v0); a1 = fmaxf(a1, v1); a2 = fmaxf(a2, v2); a3 = fmaxf(a3, v3); }
  }
  if (isSum) redsum[b * CH2 + j] = (a0 + a1) + (a2 + a3);
  else       redmax[b * CH2 + (j - 384)] = fmaxf(fmaxf(a0, a1), fmaxf(a2, a3));
}

// ---------------- K5: depthwise convs (dil 1/2/3) + GELU gate, LDS-tiled ----------------
#define TH 16
__global__ __launch_bounds__(256)
void k_dwgelu(const unsigned short* __restrict__ p,
              const float* __restrict__ wd1, const float* __restrict__ wd2,
              const float* __restrict__ wd3, unsigned short* __restrict__ g) {
  __shared__ unsigned lds[(18 + 20 + 22) * 88];   // 21120 B
  unsigned* la = lds;                // 18 rows (global y0-1 .. y0+16)
  unsigned* l2 = lds + 18 * 88;      // 20 rows (y0-2 .. y0+17)
  unsigned* l3 = lds + 38 * 88;      // 22 rows (y0-3 .. y0+18)

  int rg = blockIdx.x, c = blockIdx.y, b = blockIdx.z;
  int y0 = rg * TH;
  int tid = threadIdx.x;

  const unsigned short* pa = p + ((size_t)(b * PCH) + c) * PPS;
  const unsigned* srcA = (const unsigned*)(pa + (size_t)(y0 + 2) * PROW);
  const unsigned* src2 = (const unsigned*)(pa + (size_t)96 * PPS + (size_t)(y0 + 1) * PROW);
  const unsigned* src3 = (const unsigned*)(pa + (size_t)192 * PPS + (size_t)y0 * PROW);
  for (int i = tid; i < 18 * 88; i += 256) la[i] = srcA[i];
  for (int i = tid; i < 20 * 88; i += 256) l2[i] = src2[i];
  for (int i = tid; i < 22 * 88; i += 256) l3[i] = src3[i];

  float w1r[9], w2r[9], w3r[9];
  #pragma unroll
  for (int i = 0; i < 9; ++i) { w1r[i] = wd1[c * 9 + i]; w2r[i] = wd2[c * 9 + i]; w3r[i] = wd3[c * 9 + i]; }
  __syncthreads();

  int oy = tid >> 4;            // 0..15
  int cg = tid & 15;
  int ox0 = cg * 10;            // 0..150
  int ub = 3 + (ox0 >> 1);      // uint col base for a/g2 (px col 6+ox0)
  int ub3 = 2 + (ox0 >> 1);     // uint col base for g3  (px col 4+ox0)

  float acc_a[10], acc_g[10];
  #pragma unroll
  for (int i = 0; i < 10; ++i) { acc_a[i] = 0.f; acc_g[i] = 0.f; }

  // plane a (dil 1)
  #pragma unroll
  for (int ky = 0; ky < 3; ++ky) {
    const unsigned* rp = la + (oy + ky) * 88 + ub;
    float v[14];
    #pragma unroll
    for (int u = 0; u < 7; ++u) { unsigned d = rp[u]; v[2 * u] = bf2f(d & 0xFFFFu); v[2 * u + 1] = bf2f(d >> 16); }
    #pragma unroll
    for (int kx = 0; kx < 3; ++kx) {
      float wv = w1r[ky * 3 + kx];
      #pragma unroll
      for (int i = 0; i < 10; ++i) acc_a[i] += wv * v[i + kx + 1];
    }
  }
  // plane g2 (dil 2)
  #pragma unroll
  for (int ky = 0; ky < 3; ++ky) {
    const unsigned* rp = l2 + (oy + 2 * ky) * 88 + ub;
    float v[14];
    #pragma unroll
    for (int u = 0; u < 7; ++u) { unsigned d = rp[u]; v[2 * u] = bf2f(d & 0xFFFFu); v[2 * u + 1] = bf2f(d >> 16); }
    #pragma unroll
    for (int kx = 0; kx < 3; ++kx) {
      float wv = w2r[ky * 3 + kx];
      #pragma unroll
      for (int i = 0; i < 10; ++i) acc_g[i] += wv * v[i + 2 * kx];
    }
  }
  // plane g3 (dil 3)
  #pragma unroll
  for (int ky = 0; ky < 3; ++ky) {
    const unsigned* rp = l3 + (oy + 3 * ky) * 88 + ub3;
    float v[18];
    #pragma unroll
    for (int u = 0; u < 9; ++u) { unsigned d = rp[u]; v[2 * u] = bf2f(d & 0xFFFFu); v[2 * u + 1] = bf2f(d >> 16); }
    #pragma unroll
    for (int kx = 0; kx < 3; ++kx) {
      float wv = w3r[ky * 3 + kx];
      #pragma unroll
      for (int i = 0; i < 10; ++i) acc_g[i] += wv * v[i + 3 * kx + 1];
    }
  }

  unsigned short* gp = g + ((size_t)(b * HID) + c) * HW + (size_t)(y0 + oy) * WIDTH + ox0;
  #pragma unroll
  for (int j = 0; j < 5; ++j) {
    float a0 = acc_a[2 * j], a1 = acc_a[2 * j + 1];
    float g0 = 0.5f * a0 * (1.f + erff(a0 * 0.70710678118f)) * acc_g[2 * j];
    float g1 = 0.5f * a1 * (1.f + erff(a1 * 0.70710678118f)) * acc_g[2 * j + 1];
    ((unsigned*)gp)[j] = (unsigned)f2bf(g0) | ((unsigned)f2bf(g1) << 16);
  }
}

// ---------------- K6: GEMM2 (96->384) channel-paired + residual fuse ----------------
// Block: 64 channel-pairs (rows mo..mo+63 AND mo+192..mo+255) x 128 spatial.
// A read directly from L2-resident bf16 w_out (no Alds); each x element read ONCE,
// both outputs written by the same thread.
#define G2_ST 104
__global__ __launch_bounds__(256, 4)
void k_gemm2(const unsigned short* __restrict__ g, const unsigned short* __restrict__ wo,
             const float* __restrict__ x1, const float* __restrict__ x2,
             const float* __restrict__ cw, float* __restrict__ out) {
  __shared__ short Blds[128 * G2_ST];
  int tid = threadIdx.x;
  int mo = blockIdx.x * 64;          // channel-pair base: 0,64,128
  int ns = blockIdx.y * 128;
  int b = blockIdx.z;
  int lane = tid & 63, wid = tid >> 6;
  int quad = lane >> 4, l15 = lane & 15;
  int wn = wid;                      // 4 waves x 32 spatial cols

  // stage B: g[0..95][ns..ns+127] transposed into Blds[s][k]
  const unsigned short* gb = g + (size_t)b * HID * HW;
  #pragma unroll
  for (int it = 0; it < 3; ++it) {
    int idx = it * 256 + tid;
    int sg = idx & 31, cg = idx >> 5;
    int c4 = cg * 4, s4 = sg * 4;
    const unsigned short* src = gb + (size_t)c4 * HW + ns + s4;
    uint2 r0 = *(const uint2*)(src);
    uint2 r1 = *(const uint2*)(src + HW);
    uint2 r2 = *(const uint2*)(src + 2 * HW);
    uint2 r3 = *(const uint2*)(src + 3 * HW);
    unsigned short e0[4] = {(unsigned short)r0.x, (unsigned short)(r0.x >> 16), (unsigned short)r0.y, (unsigned short)(r0.y >> 16)};
    unsigned short e1[4] = {(unsigned short)r1.x, (unsigned short)(r1.x >> 16), (unsigned short)r1.y, (unsigned short)(r1.y >> 16)};
    unsigned short e2[4] = {(unsigned short)r2.x, (unsigned short)(r2.x >> 16), (unsigned short)r2.y, (unsigned short)(r2.y >> 16)};
    unsigned short e3[4] = {(unsigned short)r3.x, (unsigned short)(r3.x >> 16), (unsigned short)r3.y, (unsigned short)(r3.y >> 16)};
    #pragma unroll
    for (int j = 0; j < 4; ++j) {
      unsigned int lo = (unsigned int)e0[j] | ((unsigned int)e1[j] << 16);
      unsigned int hi = (unsigned int)e2[j] | ((unsigned int)e3[j] << 16);
      *(uint2*)&Blds[(s4 + j) * G2_ST + c4] = make_uint2(lo, hi);
    }
  }
  __syncthreads();

  f32x4 accL[4][2], accH[4][2];
  #pragma unroll
  for (int i = 0; i < 4; ++i) {
    #pragma unroll
    for (int j = 0; j < 2; ++j) {
      accL[i][j] = (f32x4){0.f, 0.f, 0.f, 0.f};
      accH[i][j] = (f32x4){0.f, 0.f, 0.f, 0.f};
    }
  }
  #pragma unroll
  for (int ks = 0; ks < 3; ++ks) {
    int kof = ks * 32 + quad * 8;
    bf16x8 b0 = *(const bf16x8*)&Blds[(wn * 32 + l15) * G2_ST + kof];
    bf16x8 b1 = *(const bf16x8*)&Blds[(wn * 32 + 16 + l15) * G2_ST + kof];
    #pragma unroll
    for (int mt = 0; mt < 4; ++mt) {
      const unsigned short* wr = wo + (size_t)(mo + mt * 16 + l15) * HID + kof;
      bf16x8 aL = *(const bf16x8*)(wr);
      bf16x8 aH = *(const bf16x8*)(wr + (size_t)DIM * HID);
      accL[mt][0] = __builtin_amdgcn_mfma_f32_16x16x32_bf16(aL, b0, accL[mt][0], 0, 0, 0);
      accL[mt][1] = __builtin_amdgcn_mfma_f32_16x16x32_bf16(aL, b1, accL[mt][1], 0, 0, 0);
      accH[mt][0] = __builtin_amdgcn_mfma_f32_16x16x32_bf16(aH, b0, accH[mt][0], 0, 0, 0);
      accH[mt][1] = __builtin_amdgcn_mfma_f32_16x16x32_bf16(aH, b1, accH[mt][1], 0, 0, 0);
    }
  }

  // epilogue: one v1/v2 load pair feeds BOTH outputs
  const float* cwb = cw + b * CH2;
  #pragma unroll
  for (int mt = 0; mt < 4; ++mt) {
    #pragma unroll
    for (int r = 0; r < 4; ++r) {
      int c = mo + mt * 16 + quad * 4 + r;
      float cw0v = cwb[c];          // gates x1 into out_x2
      float cw1v = cwb[c + DIM];    // gates x2 into out_x1
      #pragma unroll
      for (int nt = 0; nt < 2; ++nt) {
        int s = ns + wn * 32 + nt * 16 + l15;
        size_t coff = ((size_t)b * DIM + c) * HW + s;
        float v1 = x1[coff], v2 = x2[coff];
        out[OUTN + coff] = v2 + 0.5f * cw0v * v1 + 0.5f * accL[mt][nt][r];  // out_x2 (sw0)
        out[coff]        = v1 + 0.5f * cw1v * v2 + 0.5f * accH[mt][nt][r];  // out_x1 (sw1)
      }
    }
  }
}

extern "C" void kernel_launch(void* const* d_in, const int* in_sizes, int n_in,
                              void* d_out, int out_size, void* d_ws, size_t ws_size,
                              hipStream_t stream) {
  const float* x1 = (const float*)d_in[0];
  const float* x2 = (const float*)d_in[1];
  const float* mlp_w1 = (const float*)d_in[2];
  const float* mlp_b1 = (const float*)d_in[3];
  const float* mlp_w2 = (const float*)d_in[4];
  const float* mlp_b2 = (const float*)d_in[5];
  const float* w_in = (const float*)d_in[6];
  const float* w_dw1 = (const float*)d_in[7];
  const float* w_dw2 = (const float*)d_in[8];
  const float* w_dw3 = (const float*)d_in[9];
  const float* w_out = (const float*)d_in[10];
  float* out = (float*)d_out;

  char* ws = (char*)d_ws;
  float* redsum       = (float*)(ws + 0);           // 3072 f
  float* redmax       = (float*)(ws + 12288);       // 3072 f
  float* h1           = (float*)(ws + 24576);       // 6144 f
  float* cw           = (float*)(ws + 49152);       // 3072 f
  unsigned short* p = (unsigned short*)(ws + 65536);             // 8*288*29216 bf16
  char* gbase = ws + 65536 + 134627328;
  unsigned short* g = (unsigned short*)gbase;                    // 8*96*25600 bf16
  // partial (4.92 MB) and wA (221 KB) overlap g's region: both are dead before
  // k_dwgelu writes g (stream-ordered), so no extra workspace is needed.
  float* partial      = (float*)gbase;                           // 200*8*768 f
  unsigned short* wA  = (unsigned short*)(gbase + 8388608);      // 288*384 bf16
  // wOut (74 KB) lives in the p region: p is dead after k_dwgelu, and k_prep2
  // runs after k_dwgelu in stream order, before k_gemm2 reads it.
  unsigned short* wOut = (unsigned short*)(ws + 65536);          // 384*96 bf16

  k_prep   <<<dim3(108),         dim3(256), 0, stream>>>(w_in, wA);
  k_padzero<<<dim3(2304),        dim3(256), 0, stream>>>(p);
  k_gemm1  <<<dim3(200, 2, 8),   dim3(256), 0, stream>>>(x1, x2, wA, p, partial);
  k_reduce <<<dim3(24),          dim3(256), 0, stream>>>(partial, redsum, redmax);
  k_mlp1   <<<dim3(3, 8),        dim3(256), 0, stream>>>(redsum, redmax, mlp_w1, mlp_b1, h1);
  k_mlp2   <<<dim3(2, 8),        dim3(256), 0, stream>>>(h1, mlp_w2, mlp_b2, cw);
  k_dwgelu <<<dim3(10, 96, 8),   dim3(256), 0, stream>>>(p, w_dw1, w_dw2, w_dw3, g);
  k_prep2  <<<dim3(36),          dim3(256), 0, stream>>>(w_out, wOut);
  k_gemm2  <<<dim3(3, 200, 8),   dim3(256), 0, stream>>>(g, wOut, x1, x2, cw, out);
}